// Round 4
// baseline (377.302 us; speedup 1.0000x reference)
//
#include <hip/hip_runtime.h>
#include <hip/hip_bf16.h>
#include <cstdint>

typedef __attribute__((ext_vector_type(8))) short short8;
typedef __attribute__((ext_vector_type(4))) float floatx4;

#define NC   5
#define PP   196
#define DD   384
#define MM   512
#define ROWS (MM * PP)     /* 100352 = 1568 * 64 exactly */
#define NRB  1568
#define BR   64            /* rows per block: load:MFMA 1:4, B L2 traffic 1.2 GB (R3@BR32: 2.4GB = 57% of L2 peak) */
#define EPSN 1e-12f

/* unified column space: 5*196=980 real cols padded to 1024 = 16 tiles x 64 (4 ct x 16).
   cols >= 980 replicate col 979 (class 4): max-invariant duplicates.
   swizzled B: [tile 16][kk 12][ct 4][64 lanes * 16 B]; lane holds
   col = t*64 + ct*16 + (lane&15), k = kk*32 + (lane>>4)*8 + e. */
#define NTILES      16
#define TILE_BYTES  49152   /* 12 * 4 * 1024 */
#define KSTEP_BYTES 4096

/* monotone float <-> uint encoding so atomicMax(unsigned) orders like float */
__device__ __forceinline__ unsigned enc_f(float f) {
    unsigned u = __float_as_uint(f);
    return (u & 0x80000000u) ? ~u : (u | 0x80000000u);
}
__device__ __forceinline__ float dec_f(unsigned u) {
    unsigned b = (u & 0x80000000u) ? (u ^ 0x80000000u) : ~u;
    return __uint_as_float(b);
}
#define ENC_NEG_INF 0x007FFFFFu

__device__ __forceinline__ int cls_of(int col) {
    return (col >= 784) ? 4 : (col >= 588) ? 3 : (col >= 392) ? 2 : (col >= 196) ? 1 : 0;
}

/* ---- pass 1a: 1/||support_row|| (980 rows) ---- */
__global__ __launch_bounds__(256) void k_norm0(const float* __restrict__ sup,
                                               float* __restrict__ sinv) {
    int wid = threadIdx.x >> 6, lane = threadIdx.x & 63;
    int r = blockIdx.x * 4 + wid;
    if (r >= NC * PP) return;
    const float* src = sup + (size_t)r * DD;
    float s = 0.f;
    #pragma unroll
    for (int j = 0; j < 6; ++j) { float v = src[lane + j * 64]; s += v * v; }
    #pragma unroll
    for (int off = 1; off < 64; off <<= 1) s += __shfl_xor(s, off, 64);
    if (lane == 0) sinv[r] = 1.0f / fmaxf(sqrtf(s), EPSN);
}

/* ---- pass 1b: normalize + swizzle support into MFMA fragment order ---- */
__global__ __launch_bounds__(256) void k_swz(const float* __restrict__ sup,
                                             const float* __restrict__ sinv,
                                             __hip_bfloat16* __restrict__ snw) {
    int s = blockIdx.x * 256 + threadIdx.x;       /* 49152 slices of 16 B */
    int lane = s & 63;
    int r1 = s >> 6;
    int ct = r1 & 3;
    int r2 = r1 >> 2;
    int kk = r2 % 12;
    int t  = r2 / 12;                              /* 0..15 global col tile */
    int c16 = lane & 15, quad = lane >> 4;
    int col = t * 64 + ct * 16 + c16;              /* global col */
    if (col > NC * PP - 1) col = NC * PP - 1;      /* replicate last col: max-invariant */
    int srow = col;                                /* [c][196] concat == global col */
    const float* sp = sup + (size_t)srow * DD + kk * 32 + quad * 8;
    float inv = sinv[srow];
    alignas(16) __hip_bfloat16 hb[8];
    #pragma unroll
    for (int e = 0; e < 8; ++e) hb[e] = __float2bfloat16(sp[e] * inv);
    *(uint4*)((char*)snw + (size_t)s * 16) = *(const uint4*)hb;
}

/* ---- main: one block per 64-row strip. A(query) in LDS fragment order,
        CONFLICT-FREE staging (slot == lane -> contiguous 1KB ds_writes; R3's
        pattern was an 8-way write conflict, 4.2M cycles). Waves stream B from
        L2 (depth-3, 2-step cover) and double-buffer A fragments (ds_read for
        step s+1 issued before step s's 16 MFMAs -> the ~120cy lgkm stall that
        capped every round at ~10% per-wave MFMA density is overlapped).
        SWAPPED operands: D = B_sup * A_qry -> col-max = 15 fmax + 2 shuffles.
        NO barriers in the main loop. ---- */
__global__ __launch_bounds__(256, 2) void k_gemm_max(const float* __restrict__ q,
                                                     const __hip_bfloat16* __restrict__ snw,
                                                     float* __restrict__ rowmaxg) {
    /* As fragment order: [kk 12][rt 4][lane 64][8 bf16] = 49152 B */
    __shared__ __hip_bfloat16 As[12 * 4 * 64 * 8];
    __shared__ unsigned rmax[BR * NC];
    __shared__ float rss[BR];

    const int tid  = threadIdx.x;
    const int row0 = blockIdx.x * BR;
    const int lane = tid & 63;
    const int wav  = tid >> 6;

    for (int i = tid; i < BR * NC; i += 256) rmax[i] = ENC_NEG_INF;

    /* ---- A staging: wave w stages rows w*16..w*16+15 (rt = w).
            lane l: c16 = l&15 (row-within-16), quad = l>>4 (k-subchunk).
            Write slot = lane -> each ds_write_b128 is a contiguous 1KB burst
            (conflict-free). k = i*32 + quad*8 + e. Fused row sumsq via
            shfl 16/32. Non-temporal: query must not evict B from L2. */
    {
        const int c16  = lane & 15;
        const int quad = lane >> 4;
        const int arow = wav * 16 + c16;
        const float* src = q + (size_t)(row0 + arow) * DD + quad * 8;
        float ss = 0.f;
        #pragma unroll
        for (int i = 0; i < 12; ++i) {
            const floatx4* p = (const floatx4*)(src + i * 32);
            floatx4 x0 = __builtin_nontemporal_load(p);
            floatx4 x1 = __builtin_nontemporal_load(p + 1);
            ss += x0.x*x0.x + x0.y*x0.y + x0.z*x0.z + x0.w*x0.w
                + x1.x*x1.x + x1.y*x1.y + x1.z*x1.z + x1.w*x1.w;
            alignas(16) __hip_bfloat16 hb[8];
            hb[0] = __float2bfloat16(x0.x); hb[1] = __float2bfloat16(x0.y);
            hb[2] = __float2bfloat16(x0.z); hb[3] = __float2bfloat16(x0.w);
            hb[4] = __float2bfloat16(x1.x); hb[5] = __float2bfloat16(x1.y);
            hb[6] = __float2bfloat16(x1.z); hb[7] = __float2bfloat16(x1.w);
            *(uint4*)&As[((i * 4 + wav) * 64 + lane) * 8] = *(const uint4*)hb;
        }
        ss += __shfl_xor(ss, 16, 64);
        ss += __shfl_xor(ss, 32, 64);
        if (quad == 0) rss[arow] = ss;
    }

    /* B preload (kk 0..2 of this wave's first tile) overlaps the barrier */
    const char* bbase = (const char*)snw + (size_t)wav * TILE_BYTES + (size_t)lane * 16;
    short8 b0[4], b1[4], b2[4], a[2][4];

    #define BFETCH(buf, nk)                                                          \
        do { const char* p_ = bbase + (nk) * KSTEP_BYTES;                            \
            _Pragma("unroll")                                                        \
            for (int ct = 0; ct < 4; ++ct)                                           \
                buf[ct] = *(const short8*)(p_ + ct * 1024);                          \
        } while (0)

    #define BFETCHX(buf, nkx)                                                        \
        do { if (g + 4 < NTILES) {                                                   \
            const char* p_ = bbase + 4 * TILE_BYTES + (nkx) * KSTEP_BYTES;           \
            _Pragma("unroll")                                                        \
            for (int ct = 0; ct < 4; ++ct)                                           \
                buf[ct] = *(const short8*)(p_ + ct * 1024);                          \
        } } while (0)

    #define AFETCH(pre, kkn)                                                         \
        do { _Pragma("unroll")                                                       \
            for (int rt = 0; rt < 4; ++rt)                                           \
                a[pre][rt] = *(const short8*)&As[(((kkn) * 4 + rt) * 64 + lane) * 8];\
        } while (0)

    /* swapped operands: A-operand = B(support cols -> D rows), B-operand = A(query rows -> D cols) */
    #define MFMAS(use, buf)                                                          \
        do { _Pragma("unroll")                                                       \
            for (int ct = 0; ct < 4; ++ct)                                           \
                _Pragma("unroll")                                                    \
                for (int rt = 0; rt < 4; ++rt)                                       \
                    acc[ct][rt] = __builtin_amdgcn_mfma_f32_16x16x32_bf16(           \
                        buf[ct], a[use][rt], acc[ct][rt], 0, 0, 0);                  \
        } while (0)

    /* step s: prefetch a[(s+1)&1] <- kk s+1, run 16 MFMAs on a[s&1], refill buf (use-then-write) */
    #define STEP(use, pre, kpre, buf, nk)   do { AFETCH(pre, kpre); MFMAS(use, buf); BFETCH(buf, nk);   } while (0)
    #define STEPX(use, pre, kpre, buf, nkx) do { AFETCH(pre, kpre); MFMAS(use, buf); BFETCHX(buf, nkx); } while (0)

    BFETCH(b0, 0);
    BFETCH(b1, 1);
    BFETCH(b2, 2);

    __syncthreads();                            /* the ONLY barrier before the epilogue */

    AFETCH(0, 0);                               /* a[0] = kk0 fragments (tile-invariant) */

    #pragma unroll 1
    for (int g = wav; g < NTILES; g += 4) {
        floatx4 acc[4][4];
        #pragma unroll
        for (int i = 0; i < 4; ++i)
            #pragma unroll
            for (int j = 0; j < 4; ++j) acc[i][j] = (floatx4){0.f, 0.f, 0.f, 0.f};

        /* 12 steps, fully unrolled; a-parity alternates, b rotates mod 3.
           Last step prefetches kk0 into a[0] -> next tile's entry invariant. */
        STEP (0, 1, 1,  b0, 3);
        STEP (1, 0, 2,  b1, 4);
        STEP (0, 1, 3,  b2, 5);
        STEP (1, 0, 4,  b0, 6);
        STEP (0, 1, 5,  b1, 7);
        STEP (1, 0, 6,  b2, 8);
        STEP (0, 1, 7,  b0, 9);
        STEP (1, 0, 8,  b1, 10);
        STEP (0, 1, 9,  b2, 11);
        STEPX(1, 0, 10, b0, 0);
        STEPX(0, 1, 11, b1, 1);
        STEPX(1, 0, 0,  b2, 2);

        /* ---- epilogue: per-class col-max. Swapped C layout:
                D row (support col) = g*64 + ct*16 + (lane>>4)*4 + reg,
                D col (query row)   = rt*16 + (lane&15).
                Boundary tiles (g=3,6,9,12; exactly one per wave) split at chi*196.
                Overlaps the already-issued next-tile B loads. ---- */
        {
            const int colbase = g * 64;
            int ce = colbase + 63; if (ce > NC * PP - 1) ce = NC * PP - 1;
            const int clo = cls_of(colbase), chi = cls_of(ce);
            const int quad = lane >> 4;
            if (clo == chi) {                      /* common case: single class */
                #pragma unroll
                for (int rt = 0; rt < 4; ++rt) {
                    float mx = acc[0][rt][0];
                    #pragma unroll
                    for (int ct = 0; ct < 4; ++ct)
                        #pragma unroll
                        for (int reg = 0; reg < 4; ++reg)
                            if (ct | reg) mx = fmaxf(mx, acc[ct][rt][reg]);
                    mx = fmaxf(mx, __shfl_xor(mx, 16, 64));
                    mx = fmaxf(mx, __shfl_xor(mx, 32, 64));
                    if (lane < 16) atomicMax(&rmax[(rt * 16 + lane) * NC + clo], enc_f(mx));
                }
            } else {                               /* one boundary tile per wave */
                const int bnd = chi * PP;
                #pragma unroll
                for (int rt = 0; rt < 4; ++rt) {
                    float mlo = -INFINITY, mhi = -INFINITY;
                    #pragma unroll
                    for (int ct = 0; ct < 4; ++ct)
                        #pragma unroll
                        for (int reg = 0; reg < 4; ++reg) {
                            int scol = colbase + ct * 16 + quad * 4 + reg;
                            if (scol >= bnd) mhi = fmaxf(mhi, acc[ct][rt][reg]);
                            else             mlo = fmaxf(mlo, acc[ct][rt][reg]);
                        }
                    mlo = fmaxf(mlo, __shfl_xor(mlo, 16, 64));
                    mlo = fmaxf(mlo, __shfl_xor(mlo, 32, 64));
                    mhi = fmaxf(mhi, __shfl_xor(mhi, 16, 64));
                    mhi = fmaxf(mhi, __shfl_xor(mhi, 32, 64));
                    if (lane < 16) {
                        atomicMax(&rmax[(rt * 16 + lane) * NC + clo], enc_f(mlo));
                        atomicMax(&rmax[(rt * 16 + lane) * NC + chi], enc_f(mhi));
                    }
                }
            }
        }
        bbase += 4 * TILE_BYTES;
    }

    __syncthreads();
    /* rowmaxg layout [c][row] -> coalesced stores here, coalesced loads in k_top6 */
    for (int i = tid; i < BR * NC; i += 256) {
        int c = i >> 6, row = i & 63;
        float inv = 1.0f / fmaxf(sqrtf(rss[row]), EPSN);
        __builtin_nontemporal_store(dec_f(rmax[row * NC + c]) * inv,
                                    &rowmaxg[(size_t)c * ROWS + row0 + row]);
    }
}

/* ---- top-6 sum per (m, c): one wave each ---- */
__global__ __launch_bounds__(256) void k_top6(const float* __restrict__ rowmaxg,
                                              const float* __restrict__ scale,
                                              const float* __restrict__ bias,
                                              float* __restrict__ out) {
    int wav = threadIdx.x >> 6, lane = threadIdx.x & 63;
    int pair = blockIdx.x * 4 + wav;
    if (pair >= MM * NC) return;
    int m = pair / NC, c = pair % NC;
    size_t base = (size_t)c * ROWS + (size_t)m * PP;
    float v[4];
    #pragma unroll
    for (int i = 0; i < 4; ++i) {
        int p = lane + i * 64;
        v[i] = (p < PP) ? rowmaxg[base + p] : -INFINITY;
    }
    float sum = 0.f;
    for (int t = 0; t < 6; ++t) {
        float bv = v[0]; int bi = 0;
        #pragma unroll
        for (int i = 1; i < 4; ++i) { if (v[i] > bv) { bv = v[i]; bi = i; } }
        int gid = bi * 64 + lane;
        #pragma unroll
        for (int off = 1; off < 64; off <<= 1) {
            float ov = __shfl_xor(bv, off, 64);
            int og  = __shfl_xor(gid, off, 64);
            if (ov > bv || (ov == bv && og < gid)) { bv = ov; gid = og; }
        }
        sum += bv;
        if ((gid & 63) == lane) v[gid >> 6] = -INFINITY;  /* kill exactly one */
    }
    if (lane == 0) out[pair] = scale[0] * (sum + bias[0]);
}

extern "C" void kernel_launch(void* const* d_in, const int* in_sizes, int n_in,
                              void* d_out, int out_size, void* d_ws, size_t ws_size,
                              hipStream_t stream) {
    const float* support = (const float*)d_in[0];
    const float* query   = (const float*)d_in[1];
    const float* scale   = (const float*)d_in[2];
    const float* bias    = (const float*)d_in[3];
    float* out = (float*)d_out;

    char* ws = (char*)d_ws;
    __hip_bfloat16* snw = (__hip_bfloat16*)ws;             /* 16*49152 = 786432 B */
    float* sinv         = (float*)(ws + 786432);           /* 980*4 -> pad to 4096 */
    float* rowmaxg      = (float*)(ws + 786432 + 4096);    /* 5*100352*4 = 2007040 */

    hipLaunchKernelGGL(k_norm0,   dim3(245),  dim3(256), 0, stream, support, sinv);
    hipLaunchKernelGGL(k_swz,     dim3(192),  dim3(256), 0, stream, support, sinv, snw);
    hipLaunchKernelGGL(k_gemm_max,dim3(NRB),  dim3(256), 0, stream, query, snw, rowmaxg);
    hipLaunchKernelGGL(k_top6,    dim3(640),  dim3(256), 0, stream, rowmaxg, scale, bias, out);
}

// Round 5
// 309.062 us; speedup vs baseline: 1.2208x; 1.2208x over previous
//
#include <hip/hip_runtime.h>
#include <hip/hip_bf16.h>
#include <cstdint>

typedef __attribute__((ext_vector_type(8))) short short8;
typedef __attribute__((ext_vector_type(4))) float floatx4;

#define NC   5
#define PP   196
#define DD   384
#define MM   512
#define ROWS (MM * PP)     /* 100352 = 3136 * 32 exactly */
#define NRB  3136
#define BR   32            /* rows per block (R3 geometry: best measured) */
#define EPSN 1e-12f

/* unified column space: 5*196=980 real cols padded to 1024 = 16 tiles x 64 (4 ct x 16).
   cols >= 980 replicate col 979 (class 4): max-invariant duplicates.
   swizzled B: [tile 16][kk 12][ct 4][64 lanes * 16 B]; lane holds
   col = t*64 + ct*16 + (lane&15), k = kk*32 + (lane>>4)*8 + e. */
#define NTILES      16
#define TILE_BYTES  49152   /* 12 * 4 * 1024 */
#define KSTEP_BYTES 4096

/* monotone float <-> uint encoding so atomicMax(unsigned) orders like float */
__device__ __forceinline__ unsigned enc_f(float f) {
    unsigned u = __float_as_uint(f);
    return (u & 0x80000000u) ? ~u : (u | 0x80000000u);
}
__device__ __forceinline__ float dec_f(unsigned u) {
    unsigned b = (u & 0x80000000u) ? (u ^ 0x80000000u) : ~u;
    return __uint_as_float(b);
}
#define ENC_NEG_INF 0x007FFFFFu

__device__ __forceinline__ int cls_of(int col) {
    return (col >= 784) ? 4 : (col >= 588) ? 3 : (col >= 392) ? 2 : (col >= 196) ? 1 : 0;
}

/* ---- pass 1a: 1/||support_row|| (980 rows) ---- */
__global__ __launch_bounds__(256) void k_norm0(const float* __restrict__ sup,
                                               float* __restrict__ sinv) {
    int wid = threadIdx.x >> 6, lane = threadIdx.x & 63;
    int r = blockIdx.x * 4 + wid;
    if (r >= NC * PP) return;
    const float* src = sup + (size_t)r * DD;
    float s = 0.f;
    #pragma unroll
    for (int j = 0; j < 6; ++j) { float v = src[lane + j * 64]; s += v * v; }
    #pragma unroll
    for (int off = 1; off < 64; off <<= 1) s += __shfl_xor(s, off, 64);
    if (lane == 0) sinv[r] = 1.0f / fmaxf(sqrtf(s), EPSN);
}

/* ---- pass 1b: normalize + swizzle support into MFMA fragment order ---- */
__global__ __launch_bounds__(256) void k_swz(const float* __restrict__ sup,
                                             const float* __restrict__ sinv,
                                             __hip_bfloat16* __restrict__ snw) {
    int s = blockIdx.x * 256 + threadIdx.x;       /* 49152 slices of 16 B */
    int lane = s & 63;
    int r1 = s >> 6;
    int ct = r1 & 3;
    int r2 = r1 >> 2;
    int kk = r2 % 12;
    int t  = r2 / 12;                              /* 0..15 global col tile */
    int c16 = lane & 15, quad = lane >> 4;
    int col = t * 64 + ct * 16 + c16;              /* global col */
    if (col > NC * PP - 1) col = NC * PP - 1;      /* replicate last col: max-invariant */
    int srow = col;                                /* [c][196] concat == global col */
    const float* sp = sup + (size_t)srow * DD + kk * 32 + quad * 8;
    float inv = sinv[srow];
    alignas(16) __hip_bfloat16 hb[8];
    #pragma unroll
    for (int e = 0; e < 8; ++e) hb[e] = __float2bfloat16(sp[e] * inv);
    *(uint4*)((char*)snw + (size_t)s * 16) = *(const uint4*)hb;
}

/* ---- main: one block per 32-row strip (R3 geometry, 125.5us base).
        R5 = R3 + the two fixes R4 validated but drowned in spills:
        (1) CONFLICT-FREE A staging (slot==lane contiguous 1KB ds_writes;
            R4 measured SQ_LDS_BANK_CONFLICT = 0 with this scheme vs 4.2M),
        (2) A-fragment double-buffer (next step's 2 ds_read_b128 issued
            before this step's 8 MFMAs -> ~120cy lgkm stall overlapped),
        at a register budget that FITS: depth-2 B (32) + a[2][2] (16) +
        acc[4][2] (32 AGPR) ~= 110-125 combined < 128 -> 4 waves/SIMD.
        R4 lesson: b(48)+a(32)+acc(64) fully unrolled spilled (WRITE_SIZE
        2MB -> 141MB). Rolled 2-step loop keeps code + live ranges small.
        SWAPPED operands: D = B_sup * A_qry -> col-max = 15 fmax + 2 shfl.
        NO barriers in the main loop. ---- */
__global__ __launch_bounds__(256, 4) void k_gemm_max(const float* __restrict__ q,
                                                     const __hip_bfloat16* __restrict__ snw,
                                                     float* __restrict__ rowmaxg) {
    /* As fragment order: [kk 12][rt 2][lane 64][8 bf16] = 24576 B */
    __shared__ __hip_bfloat16 As[12 * 2 * 64 * 8];
    __shared__ unsigned rmax[BR * NC];
    __shared__ float rss[2 * BR];                  /* two k-half partials per row */

    const int tid  = threadIdx.x;
    const int row0 = blockIdx.x * BR;
    const int lane = tid & 63;
    const int wav  = tid >> 6;

    for (int i = tid; i < BR * NC; i += 256) rmax[i] = ENC_NEG_INF;

    /* ---- A staging: wave w covers rt = w&1 (rows rt*16..+15) and
            k-half kh = w>>1 (kk = kh*6 .. kh*6+5). lane: c16 = row-in-16,
            quad = k-subchunk. Write slot == lane -> each ds_write_b128 is a
            contiguous 1KB burst (conflict-free; R4-verified). Row sumsq
            partial per k-half, combined at the final store. */
    {
        const int c16  = lane & 15;
        const int quad = lane >> 4;
        const int rt   = wav & 1;
        const int kh   = wav >> 1;
        const int arow = rt * 16 + c16;
        const float* src = q + (size_t)(row0 + arow) * DD + kh * 192 + quad * 8;
        float ss = 0.f;
        #pragma unroll
        for (int i = 0; i < 6; ++i) {
            const floatx4* p = (const floatx4*)(src + i * 32);
            floatx4 x0 = __builtin_nontemporal_load(p);
            floatx4 x1 = __builtin_nontemporal_load(p + 1);
            ss += x0.x*x0.x + x0.y*x0.y + x0.z*x0.z + x0.w*x0.w
                + x1.x*x1.x + x1.y*x1.y + x1.z*x1.z + x1.w*x1.w;
            alignas(16) __hip_bfloat16 hb[8];
            hb[0] = __float2bfloat16(x0.x); hb[1] = __float2bfloat16(x0.y);
            hb[2] = __float2bfloat16(x0.z); hb[3] = __float2bfloat16(x0.w);
            hb[4] = __float2bfloat16(x1.x); hb[5] = __float2bfloat16(x1.y);
            hb[6] = __float2bfloat16(x1.z); hb[7] = __float2bfloat16(x1.w);
            int kk = kh * 6 + i;
            *(uint4*)&As[((kk * 2 + rt) * 64 + lane) * 8] = *(const uint4*)hb;
        }
        ss += __shfl_xor(ss, 16, 64);
        ss += __shfl_xor(ss, 32, 64);
        if (lane < 16) rss[kh * BR + rt * 16 + lane] = ss;
    }

    /* B preload (kk 0,1 of this wave's first tile) overlaps the barrier */
    const char* bbase = (const char*)snw + (size_t)wav * TILE_BYTES + (size_t)lane * 16;
    short8 b0[4], b1[4], a[2][2];

    #define BFETCH(buf, nk)                                                          \
        do { const char* p_ = bbase + (nk) * KSTEP_BYTES;                            \
            _Pragma("unroll")                                                        \
            for (int ct = 0; ct < 4; ++ct)                                           \
                buf[ct] = *(const short8*)(p_ + ct * 1024);                          \
        } while (0)

    /* refill buf with k-step nk (runtime), crossing into the next g-tile */
    #define BLOADN(buf, nkv)                                                         \
        do { int nk_ = (nkv);                                                        \
            if (nk_ < 12) {                                                          \
                const char* p_ = bbase + nk_ * KSTEP_BYTES;                          \
                _Pragma("unroll")                                                    \
                for (int ct = 0; ct < 4; ++ct)                                       \
                    buf[ct] = *(const short8*)(p_ + ct * 1024);                      \
            } else if (g + 4 < NTILES) {                                             \
                const char* p_ = bbase + 4 * TILE_BYTES + (nk_ - 12) * KSTEP_BYTES;  \
                _Pragma("unroll")                                                    \
                for (int ct = 0; ct < 4; ++ct)                                       \
                    buf[ct] = *(const short8*)(p_ + ct * 1024);                      \
            }                                                                        \
        } while (0)

    #define AFETCH(pre, kkn)                                                         \
        do { int kn_ = (kkn);                                                        \
            _Pragma("unroll")                                                        \
            for (int rt = 0; rt < 2; ++rt)                                           \
                a[pre][rt] = *(const short8*)&As[((kn_ * 2 + rt) * 64 + lane) * 8];  \
        } while (0)

    /* swapped operands: A-operand = B(support cols -> D rows), B-operand = A(query rows -> D cols) */
    #define MFMAS(use, buf)                                                          \
        do { _Pragma("unroll")                                                       \
            for (int ct = 0; ct < 4; ++ct)                                           \
                _Pragma("unroll")                                                    \
                for (int rt = 0; rt < 2; ++rt)                                       \
                    acc[ct][rt] = __builtin_amdgcn_mfma_f32_16x16x32_bf16(           \
                        buf[ct], a[use][rt], acc[ct][rt], 0, 0, 0);                  \
        } while (0)

    BFETCH(b0, 0);
    BFETCH(b1, 1);

    __syncthreads();                            /* the ONLY barrier before the epilogue */

    AFETCH(0, 0);                               /* a[0] = kk0 fragments (tile-invariant) */

    #pragma unroll 1
    for (int g = wav; g < NTILES; g += 4) {
        floatx4 acc[4][2];
        #pragma unroll
        for (int i = 0; i < 4; ++i)
            #pragma unroll
            for (int j = 0; j < 2; ++j) acc[i][j] = (floatx4){0.f, 0.f, 0.f, 0.f};

        /* rolled 2-step pipeline: prefetch a[next] before MFMAs on a[cur];
           b refilled right after use (depth-2, next-use 1 step away; TLP at
           4 waves/SIMD covers the L2 latency). Last odd step prefetches kk0
           into a[0] -> next tile entry invariant. */
        #pragma unroll 1
        for (int kk = 0; kk < 12; kk += 2) {
            AFETCH(1, kk + 1);
            MFMAS(0, b0);
            BLOADN(b0, kk + 2);
            AFETCH(0, (kk + 2 < 12) ? (kk + 2) : 0);
            MFMAS(1, b1);
            BLOADN(b1, kk + 3);
        }

        /* ---- epilogue: per-class col-max. Swapped C layout:
                D row (support col) = g*64 + ct*16 + (lane>>4)*4 + reg,
                D col (query row)   = rt*16 + (lane&15).
                Boundary tiles (g=3,6,9,12; exactly one per wave) split at chi*196.
                Overlaps the already-issued next-tile B loads. ---- */
        {
            const int colbase = g * 64;
            int ce = colbase + 63; if (ce > NC * PP - 1) ce = NC * PP - 1;
            const int clo = cls_of(colbase), chi = cls_of(ce);
            const int quad = lane >> 4;
            if (clo == chi) {                      /* common case: single class */
                #pragma unroll
                for (int rt = 0; rt < 2; ++rt) {
                    float mx = acc[0][rt][0];
                    #pragma unroll
                    for (int ct = 0; ct < 4; ++ct)
                        #pragma unroll
                        for (int reg = 0; reg < 4; ++reg)
                            if (ct | reg) mx = fmaxf(mx, acc[ct][rt][reg]);
                    mx = fmaxf(mx, __shfl_xor(mx, 16, 64));
                    mx = fmaxf(mx, __shfl_xor(mx, 32, 64));
                    if (lane < 16) atomicMax(&rmax[(rt * 16 + lane) * NC + clo], enc_f(mx));
                }
            } else {                               /* one boundary tile per wave */
                const int bnd = chi * PP;
                #pragma unroll
                for (int rt = 0; rt < 2; ++rt) {
                    float mlo = -INFINITY, mhi = -INFINITY;
                    #pragma unroll
                    for (int ct = 0; ct < 4; ++ct)
                        #pragma unroll
                        for (int reg = 0; reg < 4; ++reg) {
                            int scol = colbase + ct * 16 + quad * 4 + reg;
                            if (scol >= bnd) mhi = fmaxf(mhi, acc[ct][rt][reg]);
                            else             mlo = fmaxf(mlo, acc[ct][rt][reg]);
                        }
                    mlo = fmaxf(mlo, __shfl_xor(mlo, 16, 64));
                    mlo = fmaxf(mlo, __shfl_xor(mlo, 32, 64));
                    mhi = fmaxf(mhi, __shfl_xor(mhi, 16, 64));
                    mhi = fmaxf(mhi, __shfl_xor(mhi, 32, 64));
                    if (lane < 16) {
                        atomicMax(&rmax[(rt * 16 + lane) * NC + clo], enc_f(mlo));
                        atomicMax(&rmax[(rt * 16 + lane) * NC + chi], enc_f(mhi));
                    }
                }
            }
        }
        bbase += 4 * TILE_BYTES;
    }

    __syncthreads();
    /* rowmaxg layout [c][row] -> coalesced stores here, coalesced loads in k_top6 */
    for (int i = tid; i < BR * NC; i += 256) {
        int c = i >> 5, row = i & 31;
        float inv = 1.0f / fmaxf(sqrtf(rss[row] + rss[BR + row]), EPSN);
        __builtin_nontemporal_store(dec_f(rmax[row * NC + c]) * inv,
                                    &rowmaxg[(size_t)c * ROWS + row0 + row]);
    }
}

/* ---- top-6 sum per (m, c): one wave each ---- */
__global__ __launch_bounds__(256) void k_top6(const float* __restrict__ rowmaxg,
                                              const float* __restrict__ scale,
                                              const float* __restrict__ bias,
                                              float* __restrict__ out) {
    int wav = threadIdx.x >> 6, lane = threadIdx.x & 63;
    int pair = blockIdx.x * 4 + wav;
    if (pair >= MM * NC) return;
    int m = pair / NC, c = pair % NC;
    size_t base = (size_t)c * ROWS + (size_t)m * PP;
    float v[4];
    #pragma unroll
    for (int i = 0; i < 4; ++i) {
        int p = lane + i * 64;
        v[i] = (p < PP) ? rowmaxg[base + p] : -INFINITY;
    }
    float sum = 0.f;
    for (int t = 0; t < 6; ++t) {
        float bv = v[0]; int bi = 0;
        #pragma unroll
        for (int i = 1; i < 4; ++i) { if (v[i] > bv) { bv = v[i]; bi = i; } }
        int gid = bi * 64 + lane;
        #pragma unroll
        for (int off = 1; off < 64; off <<= 1) {
            float ov = __shfl_xor(bv, off, 64);
            int og  = __shfl_xor(gid, off, 64);
            if (ov > bv || (ov == bv && og < gid)) { bv = ov; gid = og; }
        }
        sum += bv;
        if ((gid & 63) == lane) v[gid >> 6] = -INFINITY;  /* kill exactly one */
    }
    if (lane == 0) out[pair] = scale[0] * (sum + bias[0]);
}

extern "C" void kernel_launch(void* const* d_in, const int* in_sizes, int n_in,
                              void* d_out, int out_size, void* d_ws, size_t ws_size,
                              hipStream_t stream) {
    const float* support = (const float*)d_in[0];
    const float* query   = (const float*)d_in[1];
    const float* scale   = (const float*)d_in[2];
    const float* bias    = (const float*)d_in[3];
    float* out = (float*)d_out;

    char* ws = (char*)d_ws;
    __hip_bfloat16* snw = (__hip_bfloat16*)ws;             /* 16*49152 = 786432 B */
    float* sinv         = (float*)(ws + 786432);           /* 980*4 -> pad to 4096 */
    float* rowmaxg      = (float*)(ws + 786432 + 4096);    /* 5*100352*4 = 2007040 */

    hipLaunchKernelGGL(k_norm0,   dim3(245),  dim3(256), 0, stream, support, sinv);
    hipLaunchKernelGGL(k_swz,     dim3(192),  dim3(256), 0, stream, support, sinv, snw);
    hipLaunchKernelGGL(k_gemm_max,dim3(NRB),  dim3(256), 0, stream, query, snw, rowmaxg);
    hipLaunchKernelGGL(k_top6,    dim3(640),  dim3(256), 0, stream, rowmaxg, scale, bias, out);
}